// Round 6
// baseline (370.054 us; speedup 1.0000x reference)
//
#include <hip/hip_runtime.h>
#include <hip/hip_cooperative_groups.h>
#include <math.h>

// DecoderSourceTarget: out[e] = sigmoid( dot( x[src[e], 0:128], x[dst[e], 128:256] ) )
// x: (100000, 256) fp32; edge_label_index: (2, 1e6) int; out: (1e6, 1) fp32.
//
// R6: decoder has plateaued at ~3.45 TB/s miss-path BW across 4 structural
// variants -> test the L3-residency theory: fuse cvt+decode in ONE cooperative
// kernel (convert -> grid.sync -> gather). The 51.2 MB fp16 table is written
// immediately before the gather with no inter-dispatch eviction window; if the
// plateau was HBM-side, L3-served gathers should break it. Decoder phase uses
// the best-measured R4 shape: 2 edges per 16-lane group + fdot2.

#define HIDDEN 256
#define HALF   128

typedef _Float16 half8 __attribute__((ext_vector_type(8)));
typedef _Float16 half4 __attribute__((ext_vector_type(4)));
typedef _Float16 half2_t __attribute__((ext_vector_type(2)));

namespace cg = cooperative_groups;

__device__ __forceinline__ float dot8(half8 a, half8 b)
{
    float acc = 0.f;
    #pragma unroll
    for (int j = 0; j < 4; ++j) {
        half2_t aj = { a[2*j], a[2*j+1] };
        half2_t bj = { b[2*j], b[2*j+1] };
        acc = __builtin_amdgcn_fdot2(aj, bj, acc, false);
    }
    return acc;
}

__global__ __launch_bounds__(256, 8) void fused_decoder_kernel(
    const float* __restrict__ x,
    const int* __restrict__ eidx,   // [2, n_edges] flattened (int32)
    float* __restrict__ out,
    _Float16* __restrict__ y,       // d_ws: fp16 table
    int n4, int n_edges)
{
    int t = blockIdx.x * blockDim.x + threadIdx.x;
    int nthreads = gridDim.x * blockDim.x;

    // ---- Phase 1: fp32 -> fp16 table (streaming, coalesced) ----
    const float4* x4 = (const float4*)x;
    half4* y4 = (half4*)y;
    for (int i = t; i < n4; i += nthreads) {
        float4 v = x4[i];
        half4 h;
        h[0] = (_Float16)v.x; h[1] = (_Float16)v.y;
        h[2] = (_Float16)v.z; h[3] = (_Float16)v.w;
        y4[i] = h;
    }

    cg::this_grid().sync();

    // ---- Phase 2: gather + dot + sigmoid. 16 lanes/group, 2 edges/group ----
    int lane = t & 15;
    int group0 = t >> 4;
    int gstride = nthreads >> 4;
    int total_groups = (n_edges + 1) >> 1;

    for (int g = group0; g < total_groups; g += gstride) {
        int e0 = g << 1;
        bool has2 = (e0 + 1) < n_edges;
        int e1 = has2 ? e0 + 1 : e0;

        int s0 = eidx[e0];
        int d0 = eidx[n_edges + e0];
        int s1 = eidx[e1];
        int d1 = eidx[n_edges + e1];

        // 4 independent 16B gathers, issued before any use.
        half8 a0 = ((const half8*)(y + (size_t)s0 * HIDDEN))[lane];
        half8 b0 = ((const half8*)(y + (size_t)d0 * HIDDEN + HALF))[lane];
        half8 a1 = ((const half8*)(y + (size_t)s1 * HIDDEN))[lane];
        half8 b1 = ((const half8*)(y + (size_t)d1 * HIDDEN + HALF))[lane];

        float acc0 = dot8(a0, b0);
        float acc1 = dot8(a1, b1);

        #pragma unroll
        for (int off = 8; off > 0; off >>= 1) {
            acc0 += __shfl_down(acc0, off, 16);
            acc1 += __shfl_down(acc1, off, 16);
        }

        if (lane == 0) {
            float r0 = 1.0f / (1.0f + __expf(-acc0));
            float r1 = 1.0f / (1.0f + __expf(-acc1));
            if (has2) ((float2*)out)[g] = make_float2(r0, r1);
            else      out[e0] = r0;
        }
    }
}

// ---------- Fallback path (two kernels, R4-best) ----------

__global__ __launch_bounds__(256) void cvt_fp16_kernel(
    const float* __restrict__ x, _Float16* __restrict__ y, int n4)
{
    int t = blockIdx.x * blockDim.x + threadIdx.x;
    int stride = gridDim.x * blockDim.x;
    const float4* x4 = (const float4*)x;
    half4* y4 = (half4*)y;
    for (int i = t; i < n4; i += stride) {
        float4 v = x4[i];
        half4 h;
        h[0] = (_Float16)v.x; h[1] = (_Float16)v.y;
        h[2] = (_Float16)v.z; h[3] = (_Float16)v.w;
        y4[i] = h;
    }
}

__global__ __launch_bounds__(256) void decoder_fp16_kernel(
    const _Float16* __restrict__ y,
    const int* __restrict__ eidx,
    float* __restrict__ out,
    int n_edges)
{
    int tid   = blockIdx.x * blockDim.x + threadIdx.x;
    int group = tid >> 4;
    int lane  = tid & 15;
    int e0 = group * 2;
    if (e0 >= n_edges) return;
    bool has2 = (e0 + 1) < n_edges;
    int e1 = has2 ? (e0 + 1) : e0;

    int s0 = eidx[e0];
    int d0 = eidx[n_edges + e0];
    int s1 = eidx[e1];
    int d1 = eidx[n_edges + e1];

    half8 a0 = ((const half8*)(y + (size_t)s0 * HIDDEN))[lane];
    half8 b0 = ((const half8*)(y + (size_t)d0 * HIDDEN + HALF))[lane];
    half8 a1 = ((const half8*)(y + (size_t)s1 * HIDDEN))[lane];
    half8 b1 = ((const half8*)(y + (size_t)d1 * HIDDEN + HALF))[lane];

    float acc0 = dot8(a0, b0);
    float acc1 = dot8(a1, b1);

    #pragma unroll
    for (int off = 8; off > 0; off >>= 1) {
        acc0 += __shfl_down(acc0, off, 16);
        acc1 += __shfl_down(acc1, off, 16);
    }

    if (lane == 0) {
        float r0 = 1.0f / (1.0f + __expf(-acc0));
        float r1 = 1.0f / (1.0f + __expf(-acc1));
        if (has2) ((float2*)out)[group] = make_float2(r0, r1);
        else      out[e0] = r0;
    }
}

__global__ __launch_bounds__(256) void decoder_fp32_kernel(
    const float* __restrict__ x,
    const int* __restrict__ eidx,
    float* __restrict__ out,
    int n_edges)
{
    int tid  = blockIdx.x * blockDim.x + threadIdx.x;
    int edge = tid >> 5;
    int lane = tid & 31;
    if (edge >= n_edges) return;

    int s = eidx[edge];
    int d = eidx[n_edges + edge];

    const float4* sp = (const float4*)(x + (size_t)s * HIDDEN) + lane;
    const float4* dp = (const float4*)(x + (size_t)d * HIDDEN + HALF) + lane;

    float4 a = *sp;
    float4 b = *dp;
    float acc = a.x * b.x + a.y * b.y + a.z * b.z + a.w * b.w;

    #pragma unroll
    for (int off = 16; off > 0; off >>= 1)
        acc += __shfl_down(acc, off, 32);

    if (lane == 0) {
        out[edge] = 1.0f / (1.0f + __expf(-acc));
    }
}

extern "C" void kernel_launch(void* const* d_in, const int* in_sizes, int n_in,
                              void* d_out, int out_size, void* d_ws, size_t ws_size,
                              hipStream_t stream)
{
    const float* x    = (const float*)d_in[0];
    const int*   eidx = (const int*)d_in[1];
    float*       out  = (float*)d_out;

    int n_edges = out_size;              // 1,000,000
    int n_elems = in_sizes[0];           // 25,600,000
    size_t need = (size_t)n_elems * 2;   // fp16 table bytes

    if (ws_size >= need) {
        _Float16* y = (_Float16*)d_ws;
        int n4 = n_elems / 4;

        // Cooperative fused path: convert -> grid.sync -> gather.
        int maxb = 0;
        hipError_t qerr = hipOccupancyMaxActiveBlocksPerMultiprocessor(
            &maxb, fused_decoder_kernel, 256, 0);

        if (qerr == hipSuccess && maxb > 0) {
            int grid = maxb * 256;           // 256 CUs on gfx950
            if (grid > 2048) grid = 2048;    // 8 blocks/CU cap (__launch_bounds__ 256,8)
            void* args[] = { (void*)&x, (void*)&eidx, (void*)&out,
                             (void*)&y, (void*)&n4, (void*)&n_edges };
            hipError_t lerr = hipLaunchCooperativeKernel(
                (void*)fused_decoder_kernel, dim3(grid), dim3(256), args, 0, stream);
            if (lerr == hipSuccess) return;
        }

        // Fallback: two-kernel path (R4-best).
        cvt_fp16_kernel<<<2048, 256, 0, stream>>>(x, y, n4);
        int groups = (n_edges + 1) / 2;
        long long total = (long long)groups * 16;
        int blocks = (int)((total + 255) / 256);
        decoder_fp16_kernel<<<blocks, 256, 0, stream>>>(y, eidx, out, n_edges);
    } else {
        int blocks = (n_edges * 32 + 255) / 256 / 1;  // 32 lanes/edge
        blocks = (n_edges + 7) / 8;                   // 8 edges per 256-thr block
        decoder_fp32_kernel<<<blocks, 256, 0, stream>>>(x, eidx, out, n_edges);
    }
}

// Round 7
// 217.771 us; speedup vs baseline: 1.6993x; 1.6993x over previous
//
#include <hip/hip_runtime.h>
#include <hip/hip_bf16.h>
#include <math.h>

// DecoderSourceTarget: out[e] = sigmoid( dot( x[src[e], 0:128], x[dst[e], 128:256] ) )
// x: (100000, 256) fp32; edge_label_index: (2, 1e6) int; out: (1e6, 1) fp32.
//
// R7: revert to R4-best flat decoder (68.3 us). Evidence across R1/R3/R5/R6:
// gather runs at ~7.4 TB/s demand-side (~12 B/cyc/CU) regardless of hit rate,
// structure, or miss volume -> per-CU L1/TCP random-gather service ceiling.
// Remaining hygiene: NT loads in cvt (x read once; don't evict y from L2/L3),
// NT store for out (never re-read). fp16 table = byte floor (bf16 absmax ~8x
// fp16's 0.0039 would breach the 0.02 threshold).

#define HIDDEN 256
#define HALF   128

typedef _Float16 half8 __attribute__((ext_vector_type(8)));
typedef _Float16 half4 __attribute__((ext_vector_type(4)));
typedef _Float16 half2_t __attribute__((ext_vector_type(2)));
typedef float    floatx4 __attribute__((ext_vector_type(4)));
typedef float    floatx2 __attribute__((ext_vector_type(2)));

__global__ __launch_bounds__(256) void cvt_fp16_kernel(
    const float* __restrict__ x, _Float16* __restrict__ y, int n4)
{
    int t = blockIdx.x * blockDim.x + threadIdx.x;
    int stride = gridDim.x * blockDim.x;
    const floatx4* x4 = (const floatx4*)x;
    half4* y4 = (half4*)y;
    for (int i = t; i < n4; i += stride) {
        floatx4 v = __builtin_nontemporal_load(x4 + i);   // x is dead after this
        half4 h;
        h[0] = (_Float16)v[0]; h[1] = (_Float16)v[1];
        h[2] = (_Float16)v[2]; h[3] = (_Float16)v[3];
        y4[i] = h;                                        // keep y cached
    }
}

__device__ __forceinline__ float dot8(half8 a, half8 b)
{
    float acc = 0.f;
    #pragma unroll
    for (int j = 0; j < 4; ++j) {
        half2_t aj = { a[2*j], a[2*j+1] };
        half2_t bj = { b[2*j], b[2*j+1] };
        acc = __builtin_amdgcn_fdot2(aj, bj, acc, false);
    }
    return acc;
}

__global__ __launch_bounds__(256) void decoder_fp16_kernel(
    const _Float16* __restrict__ y,
    const int* __restrict__ eidx,   // [2, n_edges] flattened
    float* __restrict__ out,
    int n_edges)
{
    int tid   = blockIdx.x * blockDim.x + threadIdx.x;
    int group = tid >> 4;       // 16 lanes per group, 2 edges per group
    int lane  = tid & 15;
    int e0 = group * 2;
    if (e0 >= n_edges) return;
    bool has2 = (e0 + 1) < n_edges;
    int e1 = has2 ? (e0 + 1) : e0;

    int s0 = eidx[e0];
    int d0 = eidx[n_edges + e0];
    int s1 = eidx[e1];
    int d1 = eidx[n_edges + e1];

    // 4 independent 16B gathers — issued before any use.
    half8 a0 = ((const half8*)(y + (size_t)s0 * HIDDEN))[lane];
    half8 b0 = ((const half8*)(y + (size_t)d0 * HIDDEN + HALF))[lane];
    half8 a1 = ((const half8*)(y + (size_t)s1 * HIDDEN))[lane];
    half8 b1 = ((const half8*)(y + (size_t)d1 * HIDDEN + HALF))[lane];

    float acc0 = dot8(a0, b0);
    float acc1 = dot8(a1, b1);

    #pragma unroll
    for (int off = 8; off > 0; off >>= 1) {
        acc0 += __shfl_down(acc0, off, 16);
        acc1 += __shfl_down(acc1, off, 16);
    }

    if (lane == 0) {
        float r0 = 1.0f / (1.0f + __expf(-acc0));
        float r1 = 1.0f / (1.0f + __expf(-acc1));
        if (has2) {
            floatx2 r = { r0, r1 };
            __builtin_nontemporal_store(r, (floatx2*)out + group);  // out never re-read
        } else {
            out[e0] = r0;
        }
    }
}

// fp32 fallback in case ws_size is too small for the fp16 table.
__global__ __launch_bounds__(256) void decoder_fp32_kernel(
    const float* __restrict__ x,
    const int* __restrict__ eidx,
    float* __restrict__ out,
    int n_edges)
{
    int tid  = blockIdx.x * blockDim.x + threadIdx.x;
    int edge = tid >> 5;
    int lane = tid & 31;
    if (edge >= n_edges) return;

    int s = eidx[edge];
    int d = eidx[n_edges + edge];

    const float4* sp = (const float4*)(x + (size_t)s * HIDDEN) + lane;
    const float4* dp = (const float4*)(x + (size_t)d * HIDDEN + HALF) + lane;

    float4 a = *sp;
    float4 b = *dp;
    float acc = a.x * b.x + a.y * b.y + a.z * b.z + a.w * b.w;

    #pragma unroll
    for (int off = 16; off > 0; off >>= 1)
        acc += __shfl_down(acc, off, 32);

    if (lane == 0) {
        out[edge] = 1.0f / (1.0f + __expf(-acc));
    }
}

extern "C" void kernel_launch(void* const* d_in, const int* in_sizes, int n_in,
                              void* d_out, int out_size, void* d_ws, size_t ws_size,
                              hipStream_t stream)
{
    const float* x    = (const float*)d_in[0];
    const int*   eidx = (const int*)d_in[1];
    float*       out  = (float*)d_out;

    int n_edges = out_size;              // 1,000,000
    int n_elems = in_sizes[0];           // 25,600,000
    size_t need = (size_t)n_elems * 2;   // fp16 table bytes

    if (ws_size >= need) {
        _Float16* y = (_Float16*)d_ws;
        int n4 = n_elems / 4;

        cvt_fp16_kernel<<<2048, 256, 0, stream>>>(x, y, n4);

        int groups = (n_edges + 1) / 2;             // 2 edges per 16-lane group
        long long total = (long long)groups * 16;
        int blocks = (int)((total + 255) / 256);
        decoder_fp16_kernel<<<blocks, 256, 0, stream>>>(y, eidx, out, n_edges);
    } else {
        int blocks = (n_edges + 7) / 8;             // 8 edges per 256-thr block
        decoder_fp32_kernel<<<blocks, 256, 0, stream>>>(x, eidx, out, n_edges);
    }
}